// Round 5
// baseline (11807.285 us; speedup 1.0000x reference)
//
#include <hip/hip_runtime.h>
#include <math.h>

#define NT 512

// ---- LDS (doubles) ----
#define D_YBUF 0
#define D_YCUR 64
#define D_KACC 128
#define D_H1   192    // 128
#define D_D1   320    // 128
#define D_D2   448    // 128
#define D_FB   576    // 512
#define D_T3   1088   // 512
#define D_VSIG 1600   // 16*36 = 576
#define D_CMAT 2176   // 64
#define D_HID  2240   // 17*64 = 1088
#define D_X0   3328   // 8
#define D_H2IC 3336   // 128 (ic only)
#define D_TOTAL 3464

// ---- global mirror (per-block), doubles ----
#define MB_H2 0
#define MB_WM 128       // 8*64
#define MB_U1 640       // 8*128
#define MB_U2 1664      // 8*128
#define MB_STRIDE 2688

__device__ __align__(16) double g_mirror[32 * MB_STRIDE];

static __device__ __forceinline__ double lipswish_d(double z, double* d) {
    double s = 1.0 / (1.0 + exp(-z));
    *d = 0.909 * s * (1.0 + z * (1.0 - s));
    return 0.909 * z * s;
}

extern "C" __global__ void __launch_bounds__(NT, 2)
ncde_solve(const float* __restrict__ x,
           const float* __restrict__ ic_w1, const float* __restrict__ ic_b1,
           const float* __restrict__ ic_w2, const float* __restrict__ ic_b2,
           const float* __restrict__ ic_w3, const float* __restrict__ ic_b3,
           const float* __restrict__ vf_w1, const float* __restrict__ vf_b1,
           const float* __restrict__ vf_w2, const float* __restrict__ vf_b2,
           const float* __restrict__ vf_w3, const float* __restrict__ vf_b3,
           const float* __restrict__ ro_w,  const float* __restrict__ ro_b,
           float* __restrict__ out)
{
    __shared__ double smd[D_TOTAL];

    const int t = threadIdx.x;
    const int b = blockIdx.x;
    const float* xb = x + (size_t)b * (257 * 8);
    double* mir = g_mirror + (size_t)b * MB_STRIDE;

    const float4* w3row = reinterpret_cast<const float4*>(vf_w3) + (size_t)t * 32;
    const double b3t = (double)vf_b3[t];
    const int o = t >> 2, p = t & 3;           // L1/L2 mapping
    const int a8 = t & 7, r8 = t >> 3;         // U1/U2 mapping
    const int aw = t >> 6;                     // L3/T3 wave->tangent
    const double b1r = (double)vf_b1[o];
    const double b2r = (double)vf_b2[o];

    // ==== init: X0 + logsigs ====
    if (t < 8) smd[D_X0 + t] = (double)xb[t];
    if (t < 16) {
        const float* xr = xb + t * 16 * 8;
        double cum[8], area[28], prev[8];
        #pragma unroll
        for (int i = 0; i < 8; ++i) { cum[i] = 0.0; prev[i] = (double)xr[i]; }
        #pragma unroll
        for (int q = 0; q < 28; ++q) area[q] = 0.0;
        for (int k = 1; k <= 16; ++k) {
            double dx[8];
            #pragma unroll
            for (int i = 0; i < 8; ++i) {
                double c = (double)xr[k * 8 + i];
                dx[i] = c - prev[i];
                prev[i] = c;
            }
            #pragma unroll
            for (int i = 0; i < 7; ++i) {
                #pragma unroll
                for (int j = i + 1; j < 8; ++j) {
                    int q = 7 * i - (i * (i - 1)) / 2 + (j - i - 1);
                    area[q] += 0.5 * (cum[i] * dx[j] - cum[j] * dx[i]);
                }
            }
            #pragma unroll
            for (int i = 0; i < 8; ++i) cum[i] += dx[i];
        }
        #pragma unroll
        for (int i = 0; i < 8; ++i) smd[D_VSIG + t * 36 + i] = cum[i];
        #pragma unroll
        for (int q = 0; q < 28; ++q) smd[D_VSIG + t * 36 + 8 + q] = area[q];
    }
    __syncthreads();

    // ==== ic MLP (weights straight from global) ====
    if (t < 128) {
        double acc = (double)ic_b1[t];
        #pragma unroll
        for (int e = 0; e < 8; ++e) acc += (double)ic_w1[t * 8 + e] * smd[D_X0 + e];
        double d;
        smd[D_H1 + t] = lipswish_d(acc, &d);
    }
    __syncthreads();
    if (t < 128) {
        const float4* wr = reinterpret_cast<const float4*>(ic_w2 + t * 128);
        double a0 = 0.0, a1 = 0.0, a2 = 0.0, a3 = 0.0;
        #pragma unroll
        for (int q = 0; q < 32; ++q) {
            float4 wv = wr[q];
            double2 h0 = *reinterpret_cast<const double2*>(&smd[D_H1 + 4 * q]);
            double2 h1 = *reinterpret_cast<const double2*>(&smd[D_H1 + 4 * q + 2]);
            a0 += (double)wv.x * h0.x; a1 += (double)wv.y * h0.y;
            a2 += (double)wv.z * h1.x; a3 += (double)wv.w * h1.y;
        }
        double d;
        smd[D_H2IC + t] = lipswish_d((double)ic_b2[t] + (a0 + a2) + (a1 + a3), &d);
    }
    __syncthreads();
    if (t < 64) {
        const float4* wr = reinterpret_cast<const float4*>(ic_w3 + t * 128);
        double a0 = 0.0, a1 = 0.0, a2 = 0.0, a3 = 0.0;
        #pragma unroll
        for (int q = 0; q < 32; ++q) {
            float4 wv = wr[q];
            double2 h0 = *reinterpret_cast<const double2*>(&smd[D_H2IC + 4 * q]);
            double2 h1 = *reinterpret_cast<const double2*>(&smd[D_H2IC + 4 * q + 2]);
            a0 += (double)wv.x * h0.x; a1 += (double)wv.y * h0.y;
            a2 += (double)wv.z * h1.x; a3 += (double)wv.w * h1.y;
        }
        double y0 = (double)ic_b3[t] + (a0 + a2) + (a1 + a3);
        smd[D_YCUR + t] = y0;
        smd[D_YBUF + t] = y0;
        smd[D_HID + t]  = y0;
        // CMAT for window 0
        int a = t >> 3, bb = t & 7;
        double cv = 0.0;
        if (a != bb) {
            int i = a < bb ? a : bb;
            int j = a < bb ? bb : a;
            int pidx = 7 * i - (i * (i - 1)) / 2 + (j - i - 1);
            double vv = smd[D_VSIG + 8 + pidx];
            cv = (a > bb) ? vv : -vv;
        }
        smd[D_CMAT + t] = cv;
    }
    __syncthreads();

    // ==== RK4 scan ====
    for (int w = 0; w < 16; ++w) {
        const double* v = &smd[D_VSIG + w * 36];
        for (int stage = 0; stage < 4; ++stage) {
            // ---- L1: z1[o] = W1[o,:] @ y  (split-4 over quad, shuffle reduce) ----
            {
                const float4* wq = reinterpret_cast<const float4*>(vf_w1 + o * 64 + 16 * p);
                float4 wv0 = wq[0], wv1 = wq[1], wv2 = wq[2], wv3 = wq[3];
                const float wf[16] = {wv0.x, wv0.y, wv0.z, wv0.w, wv1.x, wv1.y, wv1.z, wv1.w,
                                      wv2.x, wv2.y, wv2.z, wv2.w, wv3.x, wv3.y, wv3.z, wv3.w};
                double a0 = 0.0, a1 = 0.0;
                #pragma unroll
                for (int i = 0; i < 8; ++i) {
                    int j = (i + 2 * p) & 7;   // bank stagger
                    double2 yv = *reinterpret_cast<const double2*>(&smd[D_YBUF + 16 * p + 2 * j]);
                    a0 += (double)wf[2 * j] * yv.x;
                    a1 += (double)wf[2 * j + 1] * yv.y;
                }
                double s = a0 + a1;
                s += __shfl_xor(s, 1, 64);
                s += __shfl_xor(s, 2, 64);
                s += b1r;
                double d;
                double h = lipswish_d(s, &d);
                if (p == 0) { smd[D_H1 + o] = h; smd[D_D1 + o] = d; }
            }
            __syncthreads();
            // ---- L2: z2[o] = W2[o,:] @ h1 (split-4), H2 -> mirror ----
            {
                const float4* wq = reinterpret_cast<const float4*>(vf_w2 + o * 128 + 32 * p);
                float4 wv[8];
                #pragma unroll
                for (int q = 0; q < 8; ++q) wv[q] = wq[q];
                const float* wf = reinterpret_cast<const float*>(wv);
                double a0 = 0.0, a1 = 0.0;
                #pragma unroll
                for (int i = 0; i < 16; ++i) {
                    int j = (i + 4 * p) & 15;  // 2-way residual (free)
                    double2 hv = *reinterpret_cast<const double2*>(&smd[D_H1 + 32 * p + 2 * j]);
                    a0 += (double)wf[2 * j] * hv.x;
                    a1 += (double)wf[2 * j + 1] * hv.y;
                }
                double s = a0 + a1;
                s += __shfl_xor(s, 1, 64);
                s += __shfl_xor(s, 2, 64);
                s += b2r;
                double d;
                double h = lipswish_d(s, &d);
                if (p == 0) { smd[D_D2 + o] = d; mir[MB_H2 + o] = h; }
            }
            __threadfence_block();
            __syncthreads();
            // ---- L3: F[t] = tanh(W3[t,:] @ h2 + b3)  (h2 via VMEM mirror) ----
            {
                double a0 = 0.0, a1 = 0.0, a2 = 0.0, a3 = 0.0;
                #pragma unroll
                for (int q = 0; q < 32; ++q) {
                    float4 wv = w3row[q];
                    double2 h0 = *reinterpret_cast<const double2*>(&mir[MB_H2 + 4 * q]);
                    double2 h1 = *reinterpret_cast<const double2*>(&mir[MB_H2 + 4 * q + 2]);
                    a0 += (double)wv.x * h0.x; a1 += (double)wv.y * h0.y;
                    a2 += (double)wv.z * h1.x; a3 += (double)wv.w * h1.y;
                }
                smd[D_FB + t] = tanh(b3t + (a0 + a2) + (a1 + a3));
            }
            __syncthreads();
            // ---- WMT: wm[a][e] = sum_b CMAT[a][b]*F[b*64+e] -> mirror ----
            {
                int a = t >> 6, e = t & 63;
                double a0 = 0.0, a1 = 0.0;
                #pragma unroll
                for (int bb = 0; bb < 8; bb += 2) {
                    a0 += smd[D_CMAT + a * 8 + bb]     * smd[D_FB + bb * 64 + e];
                    a1 += smd[D_CMAT + a * 8 + bb + 1] * smd[D_FB + (bb + 1) * 64 + e];
                }
                mir[MB_WM + a * 64 + e] = a0 + a1;
            }
            __threadfence_block();
            __syncthreads();
            // ---- U1: u1[a][r] = D1[r]*(W1[r,:]@wm_a), rows r8, r8+64 ----
            {
                const float4* wra = reinterpret_cast<const float4*>(vf_w1 + r8 * 64);
                const float4* wrb = reinterpret_cast<const float4*>(vf_w1 + (r8 + 64) * 64);
                double s00 = 0.0, s01 = 0.0, s10 = 0.0, s11 = 0.0;
                #pragma unroll
                for (int q = 0; q < 16; ++q) {
                    float4 wa = wra[q], wb = wrb[q];
                    double2 m0 = *reinterpret_cast<const double2*>(&mir[MB_WM + a8 * 64 + 4 * q]);
                    double2 m1 = *reinterpret_cast<const double2*>(&mir[MB_WM + a8 * 64 + 4 * q + 2]);
                    s00 += (double)wa.x * m0.x; s01 += (double)wa.y * m0.y;
                    s00 += (double)wa.z * m1.x; s01 += (double)wa.w * m1.y;
                    s10 += (double)wb.x * m0.x; s11 += (double)wb.y * m0.y;
                    s10 += (double)wb.z * m1.x; s11 += (double)wb.w * m1.y;
                }
                mir[MB_U1 + a8 * 128 + r8]      = (s00 + s01) * smd[D_D1 + r8];
                mir[MB_U1 + a8 * 128 + r8 + 64] = (s10 + s11) * smd[D_D1 + r8 + 64];
            }
            __threadfence_block();
            __syncthreads();
            // ---- U2: u2[a][r] = D2[r]*(W2[r,:]@u1_a), rows r8, r8+64 ----
            {
                const float4* wra = reinterpret_cast<const float4*>(vf_w2 + r8 * 128);
                const float4* wrb = reinterpret_cast<const float4*>(vf_w2 + (r8 + 64) * 128);
                double s00 = 0.0, s01 = 0.0, s10 = 0.0, s11 = 0.0;
                #pragma unroll
                for (int q = 0; q < 32; ++q) {
                    float4 wa = wra[q], wb = wrb[q];
                    double2 u0 = *reinterpret_cast<const double2*>(&mir[MB_U1 + a8 * 128 + 4 * q]);
                    double2 u1 = *reinterpret_cast<const double2*>(&mir[MB_U1 + a8 * 128 + 4 * q + 2]);
                    s00 += (double)wa.x * u0.x; s01 += (double)wa.y * u0.y;
                    s00 += (double)wa.z * u1.x; s01 += (double)wa.w * u1.y;
                    s10 += (double)wb.x * u0.x; s11 += (double)wb.y * u0.y;
                    s10 += (double)wb.z * u1.x; s11 += (double)wb.w * u1.y;
                }
                mir[MB_U2 + a8 * 128 + r8]      = (s00 + s01) * smd[D_D2 + r8];
                mir[MB_U2 + a8 * 128 + r8 + 64] = (s10 + s11) * smd[D_D2 + r8 + 64];
            }
            __threadfence_block();
            __syncthreads();
            // ---- T3: t3[t] = (1-F^2)*(W3[t,:] @ u2_aw) ----
            {
                double a0 = 0.0, a1 = 0.0, a2 = 0.0, a3 = 0.0;
                #pragma unroll
                for (int q = 0; q < 32; ++q) {
                    float4 wv = w3row[q];
                    double2 u0 = *reinterpret_cast<const double2*>(&mir[MB_U2 + aw * 128 + 4 * q]);
                    double2 u1 = *reinterpret_cast<const double2*>(&mir[MB_U2 + aw * 128 + 4 * q + 2]);
                    a0 += (double)wv.x * u0.x; a1 += (double)wv.y * u0.y;
                    a2 += (double)wv.z * u1.x; a3 += (double)wv.w * u1.y;
                }
                double F = smd[D_FB + t];
                smd[D_T3 + t] = (1.0 - F * F) * ((a0 + a2) + (a1 + a3));
            }
            __syncthreads();
            // ---- combine + RK4 glue (+ next-window CMAT in stage 3) ----
            if (t < 64) {
                double g = 0.0;
                #pragma unroll
                for (int a = 0; a < 8; ++a)
                    g += v[a] * smd[D_FB + a * 64 + t] + smd[D_T3 + a * 64 + t];
                double y = smd[D_YCUR + t];
                if (stage == 0)      { smd[D_KACC + t] = g;        smd[D_YBUF + t] = y + 0.5 * g; }
                else if (stage == 1) { smd[D_KACC + t] += 2.0 * g; smd[D_YBUF + t] = y + 0.5 * g; }
                else if (stage == 2) { smd[D_KACC + t] += 2.0 * g; smd[D_YBUF + t] = y + g; }
                else {
                    double yn = y + (smd[D_KACC + t] + g) * (1.0 / 6.0);
                    smd[D_YCUR + t] = yn;
                    smd[D_YBUF + t] = yn;
                    smd[D_HID + (w + 1) * 64 + t] = yn;
                }
            } else if (t < 128 && stage == 3 && w < 15) {
                int idx = t - 64;
                int a = idx >> 3, bb = idx & 7;
                double cv = 0.0;
                if (a != bb) {
                    int i = a < bb ? a : bb;
                    int j = a < bb ? bb : a;
                    int pidx = 7 * i - (i * (i - 1)) / 2 + (j - i - 1);
                    double vv = smd[D_VSIG + (w + 1) * 36 + 8 + pidx];
                    cv = (a > bb) ? vv : -vv;
                }
                smd[D_CMAT + idx] = cv;
            }
            __syncthreads();
        }
    }

    // ==== readout ====
    for (int idx = t; idx < 544; idx += NT) {
        int s = idx >> 5, oo = idx & 31;
        double acc = (double)ro_b[oo];
        const float* wr = ro_w + oo * 64;
        const double* hr = &smd[D_HID + s * 64];
        #pragma unroll
        for (int d = 0; d < 64; ++d) acc += (double)wr[d] * hr[d];
        out[(size_t)b * 544 + idx] = (float)acc;
    }
}

extern "C" void kernel_launch(void* const* d_in, const int* in_sizes, int n_in,
                              void* d_out, int out_size, void* d_ws, size_t ws_size,
                              hipStream_t stream) {
    const float* x     = (const float*)d_in[0];
    const float* ic_w1 = (const float*)d_in[1];
    const float* ic_b1 = (const float*)d_in[2];
    const float* ic_w2 = (const float*)d_in[3];
    const float* ic_b2 = (const float*)d_in[4];
    const float* ic_w3 = (const float*)d_in[5];
    const float* ic_b3 = (const float*)d_in[6];
    const float* vf_w1 = (const float*)d_in[7];
    const float* vf_b1 = (const float*)d_in[8];
    const float* vf_w2 = (const float*)d_in[9];
    const float* vf_b2 = (const float*)d_in[10];
    const float* vf_w3 = (const float*)d_in[11];
    const float* vf_b3 = (const float*)d_in[12];
    const float* ro_w  = (const float*)d_in[13];
    const float* ro_b  = (const float*)d_in[14];
    float* out = (float*)d_out;

    int B = in_sizes[0] / (257 * 8);
    hipLaunchKernelGGL(ncde_solve, dim3(B), dim3(NT), 0, stream,
                       x, ic_w1, ic_b1, ic_w2, ic_b2, ic_w3, ic_b3,
                       vf_w1, vf_b1, vf_w2, vf_b2, vf_w3, vf_b3, ro_w, ro_b, out);
}

// Round 6
// 2221.752 us; speedup vs baseline: 5.3144x; 5.3144x over previous
//
#include <hip/hip_runtime.h>
#include <math.h>

#define NT 512

// ---- double (activation) region, offsets in doubles ----
#define D_YBUF 0
#define D_YCUR 64
#define D_KACC 128
#define D_H1   192
#define D_D1   320
#define D_H2   448
#define D_D2   576
#define D_FB   704     // 512
#define D_T3   1216    // 512
#define D_WMT  1728    // [8][68]
#define D_U1   2272    // [8][132]
#define D_U2   3328    // [8][132]
#define D_VSIG 4384    // [16][36]
#define D_CMAT 4960    // 64
#define D_HID  5024    // [17][64]
#define D_X0   6112    // 8
#define D_PART 6120    // [4][132]
#define D_TOTAL 6656

// ---- float region: packed-transposed weights (float2 units) ----
// FW1: 4096 float2: W1P[e2*128 + r] = (W1[r][2e2], W1[r][2e2+1])
// FW2: 8192 float2: W2P[c2*128 + r] = (W2[r][2c2], W2[r][2c2+1])
#define FW1 0
#define FW2 8192
#define F_TOTAL 24576

#define SMEM_BYTES (D_TOTAL * 8 + F_TOTAL * 4)

static __device__ __forceinline__ double lipswish_d(double z, double* d) {
    double s = 1.0 / (1.0 + exp(-z));
    *d = 0.909 * s * (1.0 + z * (1.0 - s));
    return 0.909 * z * s;
}

extern "C" __global__ void __launch_bounds__(NT, 1)
ncde_solve(const float* __restrict__ x,
           const float* __restrict__ ic_w1, const float* __restrict__ ic_b1,
           const float* __restrict__ ic_w2, const float* __restrict__ ic_b2,
           const float* __restrict__ ic_w3, const float* __restrict__ ic_b3,
           const float* __restrict__ vf_w1, const float* __restrict__ vf_b1,
           const float* __restrict__ vf_w2, const float* __restrict__ vf_b2,
           const float* __restrict__ vf_w3, const float* __restrict__ vf_b3,
           const float* __restrict__ ro_w,  const float* __restrict__ ro_b,
           float* __restrict__ out)
{
    extern __shared__ char smraw[];
    double* smd = reinterpret_cast<double*>(smraw);
    float*  smw = reinterpret_cast<float*>(smd + D_TOTAL);
    float2* W1P = reinterpret_cast<float2*>(smw + FW1);
    float2* W2P = reinterpret_cast<float2*>(smw + FW2);

    const int t = threadIdx.x;
    const int b = blockIdx.x;
    const float* xb = x + (size_t)b * (257 * 8);

    // ---- vf_w3 row t in registers (128 VGPRs; fits under the 256-VGPR cap) ----
    float4 w3q[32];
    {
        const float4* src = reinterpret_cast<const float4*>(vf_w3) + (size_t)t * 32;
        #pragma unroll
        for (int q = 0; q < 32; ++q) w3q[q] = src[q];
    }
    const double b3t = (double)vf_b3[t];

    // ==== Phase 1: stage ic_w2 (packed into FW2), ic_w3 (packed into FW1), X0, logsigs ====
    for (int j = t; j < 8192; j += NT) {           // ic_w2: 128x128
        int c2 = j >> 7, r = j & 127;
        smw[FW2 + 2 * j]     = ic_w2[r * 128 + 2 * c2];
        smw[FW2 + 2 * j + 1] = ic_w2[r * 128 + 2 * c2 + 1];
    }
    for (int j = t; j < 4096; j += NT) {           // ic_w3: 64x128 -> P[c2*64+o]
        int c2 = j >> 6, o = j & 63;
        smw[FW1 + 2 * j]     = ic_w3[o * 128 + 2 * c2];
        smw[FW1 + 2 * j + 1] = ic_w3[o * 128 + 2 * c2 + 1];
    }
    if (t < 8) smd[D_X0 + t] = (double)xb[t];
    if (t < 16) {
        const float* xr = xb + t * 16 * 8;
        double cum[8], area[28], prev[8];
        #pragma unroll
        for (int i = 0; i < 8; ++i) { cum[i] = 0.0; prev[i] = (double)xr[i]; }
        #pragma unroll
        for (int p = 0; p < 28; ++p) area[p] = 0.0;
        for (int k = 1; k <= 16; ++k) {
            double dx[8];
            #pragma unroll
            for (int i = 0; i < 8; ++i) {
                double c = (double)xr[k * 8 + i];
                dx[i] = c - prev[i];
                prev[i] = c;
            }
            #pragma unroll
            for (int i = 0; i < 7; ++i) {
                #pragma unroll
                for (int j = i + 1; j < 8; ++j) {
                    int p = 7 * i - (i * (i - 1)) / 2 + (j - i - 1);
                    area[p] += 0.5 * (cum[i] * dx[j] - cum[j] * dx[i]);
                }
            }
            #pragma unroll
            for (int i = 0; i < 8; ++i) cum[i] += dx[i];
        }
        #pragma unroll
        for (int i = 0; i < 8; ++i) smd[D_VSIG + t * 36 + i] = cum[i];
        #pragma unroll
        for (int p = 0; p < 28; ++p) smd[D_VSIG + t * 36 + 8 + p] = area[p];
    }
    __syncthreads();

    // ==== ic MLP ====
    if (t < 128) {
        double acc = (double)ic_b1[t];
        #pragma unroll
        for (int e = 0; e < 8; ++e) acc += (double)ic_w1[t * 8 + e] * smd[D_X0 + e];
        double d;
        smd[D_H1 + t] = lipswish_d(acc, &d);
    }
    __syncthreads();
    if (t < 128) {
        double a0 = 0.0, a1 = 0.0;
        #pragma unroll
        for (int c2 = 0; c2 < 64; ++c2) {
            float2 w = W2P[c2 * 128 + t];
            double2 h = *reinterpret_cast<const double2*>(&smd[D_H1 + 2 * c2]);
            a0 += (double)w.x * h.x;
            a1 += (double)w.y * h.y;
        }
        double d;
        smd[D_H2 + t] = lipswish_d((double)ic_b2[t] + a0 + a1, &d);
    }
    __syncthreads();
    if (t < 64) {
        double a0 = 0.0, a1 = 0.0;
        #pragma unroll
        for (int c2 = 0; c2 < 64; ++c2) {
            float2 w = W1P[c2 * 64 + t];   // ic_w3 packed at stride 64
            double2 h = *reinterpret_cast<const double2*>(&smd[D_H2 + 2 * c2]);
            a0 += (double)w.x * h.x;
            a1 += (double)w.y * h.y;
        }
        double y0 = (double)ic_b3[t] + a0 + a1;
        smd[D_YCUR + t] = y0;
        smd[D_HID + t]  = y0;
    }
    __syncthreads();

    // ==== stage vf weights (packed-transposed), init CMAT(w=0) + YBUF ====
    for (int j = t; j < 4096; j += NT) {           // vf_w1: 128x64
        int e2 = j >> 7, r = j & 127;
        smw[FW1 + 2 * j]     = vf_w1[r * 64 + 2 * e2];
        smw[FW1 + 2 * j + 1] = vf_w1[r * 64 + 2 * e2 + 1];
    }
    for (int j = t; j < 8192; j += NT) {           // vf_w2: 128x128
        int c2 = j >> 7, r = j & 127;
        smw[FW2 + 2 * j]     = vf_w2[r * 128 + 2 * c2];
        smw[FW2 + 2 * j + 1] = vf_w2[r * 128 + 2 * c2 + 1];
    }
    if (t < 64) {
        int a = t >> 3, bb = t & 7;
        double cv = 0.0;
        if (a != bb) {
            int i = a < bb ? a : bb;
            int j = a < bb ? bb : a;
            int pidx = 7 * i - (i * (i - 1)) / 2 + (j - i - 1);
            double vv = smd[D_VSIG + 8 + pidx];
            cv = (a > bb) ? vv : -vv;
        }
        smd[D_CMAT + t] = cv;
        smd[D_YBUF + t] = smd[D_YCUR + t];
    }
    __syncthreads();

    // ==== RK4 scan ====
    for (int w = 0; w < 16; ++w) {
        const double* v = &smd[D_VSIG + w * 36];
        for (int stage = 0; stage < 4; ++stage) {
            // L1 split-4: o = t&127, p = t>>7, e2 in [8p, 8p+8)
            {
                int o = t & 127, p = t >> 7;
                double a0 = 0.0, a1 = 0.0;
                #pragma unroll
                for (int k = 0; k < 8; ++k) {
                    int e2 = 8 * p + k;
                    float2 wv = W1P[e2 * 128 + o];
                    double2 yv = *reinterpret_cast<const double2*>(&smd[D_YBUF + 2 * e2]);
                    a0 += (double)wv.x * yv.x;
                    a1 += (double)wv.y * yv.y;
                }
                smd[D_PART + p * 132 + o] = a0 + a1;
            }
            __syncthreads();
            if (t < 128) {
                double s = smd[D_PART + t] + smd[D_PART + 132 + t]
                         + smd[D_PART + 264 + t] + smd[D_PART + 396 + t]
                         + (double)vf_b1[t];
                double d;
                smd[D_H1 + t] = lipswish_d(s, &d);
                smd[D_D1 + t] = d;
            }
            __syncthreads();
            // L2 split-4: c2 in [16p, 16p+16)
            {
                int o = t & 127, p = t >> 7;
                double a0 = 0.0, a1 = 0.0, a2 = 0.0, a3 = 0.0;
                #pragma unroll
                for (int k = 0; k < 16; ++k) {
                    int c2 = 16 * p + k;
                    float2 wv = W2P[c2 * 128 + o];
                    double2 hv = *reinterpret_cast<const double2*>(&smd[D_H1 + 2 * c2]);
                    if (k & 1) { a2 += (double)wv.x * hv.x; a3 += (double)wv.y * hv.y; }
                    else       { a0 += (double)wv.x * hv.x; a1 += (double)wv.y * hv.y; }
                }
                smd[D_PART + p * 132 + o] = (a0 + a2) + (a1 + a3);
            }
            __syncthreads();
            if (t < 128) {
                double s = smd[D_PART + t] + smd[D_PART + 132 + t]
                         + smd[D_PART + 264 + t] + smd[D_PART + 396 + t]
                         + (double)vf_b2[t];
                double d;
                smd[D_H2 + t] = lipswish_d(s, &d);
                smd[D_D2 + t] = d;
            }
            __syncthreads();
            // L3: F = tanh(W3 h2 + b3), row t (W3 in regs)
            {
                double a0 = 0.0, a1 = 0.0, a2 = 0.0, a3 = 0.0;
                #pragma unroll
                for (int q = 0; q < 32; ++q) {
                    float4 wv = w3q[q];
                    double2 h0 = *reinterpret_cast<const double2*>(&smd[D_H2 + 4 * q]);
                    double2 h1 = *reinterpret_cast<const double2*>(&smd[D_H2 + 4 * q + 2]);
                    a0 += (double)wv.x * h0.x;
                    a1 += (double)wv.y * h0.y;
                    a2 += (double)wv.z * h1.x;
                    a3 += (double)wv.w * h1.y;
                }
                smd[D_FB + t] = tanh(b3t + (a0 + a2) + (a1 + a3));
            }
            __syncthreads();
            // wm[a][e] = sum_b CMAT[a][b] * F[b][e]
            {
                int a = t >> 6, e = t & 63;
                double a0 = 0.0, a1 = 0.0;
                #pragma unroll
                for (int bb = 0; bb < 8; bb += 2) {
                    a0 += smd[D_CMAT + a * 8 + bb]     * smd[D_FB + bb * 64 + e];
                    a1 += smd[D_CMAT + a * 8 + bb + 1] * smd[D_FB + (bb + 1) * 64 + e];
                }
                smd[D_WMT + a * 68 + e] = a0 + a1;
            }
            __syncthreads();
            // U1[a][r] = D1[r] * (W1 @ wm_a)[r] ; thread: a=t&7, r=t>>3 (+64)
            {
                int a = t & 7, r = t >> 3;
                double s00 = 0.0, s01 = 0.0, s10 = 0.0, s11 = 0.0;
                #pragma unroll
                for (int e2 = 0; e2 < 32; ++e2) {
                    float2 wa = W1P[e2 * 128 + r];
                    float2 wb = W1P[e2 * 128 + r + 64];
                    double2 wm = *reinterpret_cast<const double2*>(&smd[D_WMT + a * 68 + 2 * e2]);
                    s00 += (double)wa.x * wm.x;
                    s01 += (double)wa.y * wm.y;
                    s10 += (double)wb.x * wm.x;
                    s11 += (double)wb.y * wm.y;
                }
                smd[D_U1 + a * 132 + r]      = (s00 + s01) * smd[D_D1 + r];
                smd[D_U1 + a * 132 + r + 64] = (s10 + s11) * smd[D_D1 + r + 64];
            }
            __syncthreads();
            // U2[a][r] = D2[r] * (W2 @ U1_a)[r]
            {
                int a = t & 7, r = t >> 3;
                double s00 = 0.0, s01 = 0.0, s10 = 0.0, s11 = 0.0;
                #pragma unroll
                for (int c2 = 0; c2 < 64; ++c2) {
                    float2 wa = W2P[c2 * 128 + r];
                    float2 wb = W2P[c2 * 128 + r + 64];
                    double2 uv = *reinterpret_cast<const double2*>(&smd[D_U1 + a * 132 + 2 * c2]);
                    s00 += (double)wa.x * uv.x;
                    s01 += (double)wa.y * uv.y;
                    s10 += (double)wb.x * uv.x;
                    s11 += (double)wb.y * uv.y;
                }
                smd[D_U2 + a * 132 + r]      = (s00 + s01) * smd[D_D2 + r];
                smd[D_U2 + a * 132 + r + 64] = (s10 + s11) * smd[D_D2 + r + 64];
            }
            __syncthreads();
            // T3[t] = (1-F^2) * (W3[t,:] @ U2_a), a = t>>6 (W3 in regs)
            {
                int a = t >> 6;
                double a0 = 0.0, a1 = 0.0, a2 = 0.0, a3 = 0.0;
                #pragma unroll
                for (int q = 0; q < 32; ++q) {
                    float4 wv = w3q[q];
                    double2 u0 = *reinterpret_cast<const double2*>(&smd[D_U2 + a * 132 + 4 * q]);
                    double2 u1 = *reinterpret_cast<const double2*>(&smd[D_U2 + a * 132 + 4 * q + 2]);
                    a0 += (double)wv.x * u0.x;
                    a1 += (double)wv.y * u0.y;
                    a2 += (double)wv.z * u1.x;
                    a3 += (double)wv.w * u1.y;
                }
                double F = smd[D_FB + t];
                smd[D_T3 + t] = (1.0 - F * F) * ((a0 + a2) + (a1 + a3));
            }
            __syncthreads();
            // combine + RK4 glue; fold next-window CMAT setup into stage 3
            if (t < 64) {
                double g = 0.0;
                #pragma unroll
                for (int a = 0; a < 8; ++a)
                    g += v[a] * smd[D_FB + a * 64 + t] + smd[D_T3 + a * 64 + t];
                double y = smd[D_YCUR + t];
                if (stage == 0)      { smd[D_KACC + t] = g;        smd[D_YBUF + t] = y + 0.5 * g; }
                else if (stage == 1) { smd[D_KACC + t] += 2.0 * g; smd[D_YBUF + t] = y + 0.5 * g; }
                else if (stage == 2) { smd[D_KACC + t] += 2.0 * g; smd[D_YBUF + t] = y + g; }
                else {
                    double yn = y + (smd[D_KACC + t] + g) * (1.0 / 6.0);
                    smd[D_YCUR + t] = yn;
                    smd[D_YBUF + t] = yn;
                    smd[D_HID + (w + 1) * 64 + t] = yn;
                }
            } else if (t < 128 && stage == 3 && w < 15) {
                int idx = t - 64;
                int a = idx >> 3, bb = idx & 7;
                double cv = 0.0;
                if (a != bb) {
                    int i = a < bb ? a : bb;
                    int j = a < bb ? bb : a;
                    int pidx = 7 * i - (i * (i - 1)) / 2 + (j - i - 1);
                    double vv = smd[D_VSIG + (w + 1) * 36 + 8 + pidx];
                    cv = (a > bb) ? vv : -vv;
                }
                smd[D_CMAT + idx] = cv;
            }
            __syncthreads();
        }
    }

    // ==== readout ====
    for (int idx = t; idx < 544; idx += NT) {
        int s = idx >> 5, o = idx & 31;
        double acc = (double)ro_b[o];
        const float* wr = ro_w + o * 64;
        const double* hr = &smd[D_HID + s * 64];
        #pragma unroll
        for (int d = 0; d < 64; ++d) acc += (double)wr[d] * hr[d];
        out[(size_t)b * 544 + idx] = (float)acc;
    }
}

extern "C" void kernel_launch(void* const* d_in, const int* in_sizes, int n_in,
                              void* d_out, int out_size, void* d_ws, size_t ws_size,
                              hipStream_t stream) {
    const float* x     = (const float*)d_in[0];
    const float* ic_w1 = (const float*)d_in[1];
    const float* ic_b1 = (const float*)d_in[2];
    const float* ic_w2 = (const float*)d_in[3];
    const float* ic_b2 = (const float*)d_in[4];
    const float* ic_w3 = (const float*)d_in[5];
    const float* ic_b3 = (const float*)d_in[6];
    const float* vf_w1 = (const float*)d_in[7];
    const float* vf_b1 = (const float*)d_in[8];
    const float* vf_w2 = (const float*)d_in[9];
    const float* vf_b2 = (const float*)d_in[10];
    const float* vf_w3 = (const float*)d_in[11];
    const float* vf_b3 = (const float*)d_in[12];
    const float* ro_w  = (const float*)d_in[13];
    const float* ro_b  = (const float*)d_in[14];
    float* out = (float*)d_out;

    int B = in_sizes[0] / (257 * 8);
    size_t shmem = (size_t)SMEM_BYTES;
    hipFuncSetAttribute(reinterpret_cast<const void*>(ncde_solve),
                        hipFuncAttributeMaxDynamicSharedMemorySize, (int)shmem);
    hipLaunchKernelGGL(ncde_solve, dim3(B), dim3(NT), shmem, stream,
                       x, ic_w1, ic_b1, ic_w2, ic_b2, ic_w3, ic_b3,
                       vf_w1, vf_b1, vf_w2, vf_b2, vf_w3, vf_b3, ro_w, ro_b, out);
}

// Round 7
// 2133.426 us; speedup vs baseline: 5.5344x; 1.0414x over previous
//
#include <hip/hip_runtime.h>
#include <math.h>

#define NT 512

// ---- double (activation) region, offsets in doubles ----
#define D_YBUF 0
#define D_YCUR 64
#define D_KACC 128
#define D_H1   192    // 128
#define D_D1   320    // 128
#define D_H2   448    // 128
#define D_D2   576    // 128
#define D_FB   704    // 512
#define D_T3   1216   // 512
#define D_VSIG 1728   // 16*36
#define D_CMAT 2304   // 64
#define D_HID  2368   // 17*64
#define D_X0   3456   // 8
#define D_B1   3464   // 128
#define D_B2   3592   // 128
#define D_SWM  3720   // 8*68  per-wave wm scratch
#define D_SU1  4264   // 8*132 per-wave u1 scratch
#define D_SU2  5320   // 8*132 per-wave u2 scratch
#define D_TOTAL 6376

// ---- float region: packed-transposed weights, float2 units, stride 132 ----
// W1P[e2*132 + r] = (W1[r][2e2], W1[r][2e2+1]),  e2<32, r<128
// W2P[c2*132 + r] = (W2[r][2c2], W2[r][2c2+1]),  c2<64, r<128
#define FW1 0          // 2*4224 floats
#define FW2 8448       // 2*8448 floats
#define F_TOTAL 25344
#define WS 132

#define SMEM_BYTES (D_TOTAL * 8 + F_TOTAL * 4)

static __device__ __forceinline__ double lipswish_d(double z, double* d) {
    double s = 1.0 / (1.0 + exp(-z));
    *d = 0.909 * s * (1.0 + z * (1.0 - s));
    return 0.909 * z * s;
}

extern "C" __global__ void __launch_bounds__(NT, 2)
ncde_solve(const float* __restrict__ x,
           const float* __restrict__ ic_w1, const float* __restrict__ ic_b1,
           const float* __restrict__ ic_w2, const float* __restrict__ ic_b2,
           const float* __restrict__ ic_w3, const float* __restrict__ ic_b3,
           const float* __restrict__ vf_w1, const float* __restrict__ vf_b1,
           const float* __restrict__ vf_w2, const float* __restrict__ vf_b2,
           const float* __restrict__ vf_w3, const float* __restrict__ vf_b3,
           const float* __restrict__ ro_w,  const float* __restrict__ ro_b,
           float* __restrict__ out)
{
    extern __shared__ char smraw[];
    double* smd = reinterpret_cast<double*>(smraw);
    float*  smw = reinterpret_cast<float*>(smd + D_TOTAL);
    float2* W1P = reinterpret_cast<float2*>(smw + FW1);
    float2* W2P = reinterpret_cast<float2*>(smw + FW2);

    const int t = threadIdx.x;
    const int b = blockIdx.x;
    const float* xb = x + (size_t)b * (257 * 8);

    // ---- vf_w3 row t resident in registers/AGPRs ----
    float4 w3q[32];
    {
        const float4* src = reinterpret_cast<const float4*>(vf_w3) + (size_t)t * 32;
        #pragma unroll
        for (int q = 0; q < 32; ++q) w3q[q] = src[q];
    }
    const double b3t = (double)vf_b3[t];
    const int o = t >> 2, p = t & 3;     // forward-path quad split
    const int wv_ = t >> 6, ln = t & 63; // tangent phase: wave wv_ owns tangent wv_

    // ==== Phase 1: stage ic_w2 (into W2P), ic_w3 (into W1P, stride 64), X0, logsigs ====
    for (int j = t; j < 8192; j += NT) {           // ic_w2: 128x128
        int c2 = j >> 7, r = j & 127;
        smw[FW2 + 2 * (c2 * WS + r)]     = ic_w2[r * 128 + 2 * c2];
        smw[FW2 + 2 * (c2 * WS + r) + 1] = ic_w2[r * 128 + 2 * c2 + 1];
    }
    for (int j = t; j < 4096; j += NT) {           // ic_w3: 64x128 -> W1P[c2*64+oo]
        int c2 = j >> 6, oo = j & 63;
        smw[FW1 + 2 * j]     = ic_w3[oo * 128 + 2 * c2];
        smw[FW1 + 2 * j + 1] = ic_w3[oo * 128 + 2 * c2 + 1];
    }
    if (t < 8) smd[D_X0 + t] = (double)xb[t];
    if (t < 16) {
        const float* xr = xb + t * 16 * 8;
        double cum[8], area[28], prev[8];
        #pragma unroll
        for (int i = 0; i < 8; ++i) { cum[i] = 0.0; prev[i] = (double)xr[i]; }
        #pragma unroll
        for (int q = 0; q < 28; ++q) area[q] = 0.0;
        for (int k = 1; k <= 16; ++k) {
            double dx[8];
            #pragma unroll
            for (int i = 0; i < 8; ++i) {
                double c = (double)xr[k * 8 + i];
                dx[i] = c - prev[i];
                prev[i] = c;
            }
            #pragma unroll
            for (int i = 0; i < 7; ++i) {
                #pragma unroll
                for (int j = i + 1; j < 8; ++j) {
                    int q = 7 * i - (i * (i - 1)) / 2 + (j - i - 1);
                    area[q] += 0.5 * (cum[i] * dx[j] - cum[j] * dx[i]);
                }
            }
            #pragma unroll
            for (int i = 0; i < 8; ++i) cum[i] += dx[i];
        }
        #pragma unroll
        for (int i = 0; i < 8; ++i) smd[D_VSIG + t * 36 + i] = cum[i];
        #pragma unroll
        for (int q = 0; q < 28; ++q) smd[D_VSIG + t * 36 + 8 + q] = area[q];
    }
    __syncthreads();

    // ==== ic MLP ====
    if (t < 128) {
        double acc = (double)ic_b1[t];
        #pragma unroll
        for (int e = 0; e < 8; ++e) acc += (double)ic_w1[t * 8 + e] * smd[D_X0 + e];
        double d;
        smd[D_H1 + t] = lipswish_d(acc, &d);
    }
    __syncthreads();
    if (t < 128) {
        double a0 = 0.0, a1 = 0.0;
        #pragma unroll
        for (int c2 = 0; c2 < 64; ++c2) {
            float2 w = W2P[c2 * WS + t];
            double2 h = *reinterpret_cast<const double2*>(&smd[D_H1 + 2 * c2]);
            a0 += (double)w.x * h.x;
            a1 += (double)w.y * h.y;
        }
        double d;
        smd[D_H2 + t] = lipswish_d((double)ic_b2[t] + a0 + a1, &d);
    }
    __syncthreads();
    if (t < 64) {
        double a0 = 0.0, a1 = 0.0;
        #pragma unroll
        for (int c2 = 0; c2 < 64; ++c2) {
            float2 w = W1P[c2 * 64 + t];   // ic_w3 packed, stride 64
            double2 h = *reinterpret_cast<const double2*>(&smd[D_H2 + 2 * c2]);
            a0 += (double)w.x * h.x;
            a1 += (double)w.y * h.y;
        }
        double y0 = (double)ic_b3[t] + a0 + a1;
        smd[D_YCUR + t] = y0;
        smd[D_HID + t]  = y0;
    }
    __syncthreads();

    // ==== stage vf weights (packed, stride 132) + biases; init CMAT(w=0) + YBUF ====
    for (int j = t; j < 4096; j += NT) {           // vf_w1: 128x64
        int e2 = j >> 7, r = j & 127;
        smw[FW1 + 2 * (e2 * WS + r)]     = vf_w1[r * 64 + 2 * e2];
        smw[FW1 + 2 * (e2 * WS + r) + 1] = vf_w1[r * 64 + 2 * e2 + 1];
    }
    for (int j = t; j < 8192; j += NT) {           // vf_w2: 128x128
        int c2 = j >> 7, r = j & 127;
        smw[FW2 + 2 * (c2 * WS + r)]     = vf_w2[r * 128 + 2 * c2];
        smw[FW2 + 2 * (c2 * WS + r) + 1] = vf_w2[r * 128 + 2 * c2 + 1];
    }
    if (t < 128) {
        smd[D_B1 + t] = (double)vf_b1[t];
        smd[D_B2 + t] = (double)vf_b2[t];
    }
    if (t < 64) {
        int a = t >> 3, bb = t & 7;
        double cv = 0.0;
        if (a != bb) {
            int i = a < bb ? a : bb;
            int j = a < bb ? bb : a;
            int pidx = 7 * i - (i * (i - 1)) / 2 + (j - i - 1);
            double vv = smd[D_VSIG + 8 + pidx];
            cv = (a > bb) ? vv : -vv;
        }
        smd[D_CMAT + t] = cv;
        smd[D_YBUF + t] = smd[D_YCUR + t];
    }
    __syncthreads();

    const double b1r = smd[D_B1 + o];
    const double b2r = smd[D_B2 + o];

    // ==== RK4 scan: 5 barriers/stage ====
    for (int w = 0; w < 16; ++w) {
        for (int stage = 0; stage < 4; ++stage) {
            // ---- A: L1 quad-split + shuffle reduce ----
            {
                double a0 = 0.0, a1 = 0.0;
                #pragma unroll
                for (int k = 0; k < 8; ++k) {
                    int e2 = 8 * p + k;
                    float2 wvv = W1P[e2 * WS + o];
                    double2 yv = *reinterpret_cast<const double2*>(&smd[D_YBUF + 2 * e2]);
                    a0 += (double)wvv.x * yv.x;
                    a1 += (double)wvv.y * yv.y;
                }
                double s = a0 + a1;
                s += __shfl_xor(s, 1, 64);
                s += __shfl_xor(s, 2, 64);
                s += b1r;
                double d;
                double h = lipswish_d(s, &d);
                if (p == 0) { smd[D_H1 + o] = h; smd[D_D1 + o] = d; }
            }
            __syncthreads();
            // ---- B: L2 quad-split + shuffle reduce ----
            {
                double a0 = 0.0, a1 = 0.0, a2 = 0.0, a3 = 0.0;
                #pragma unroll
                for (int k = 0; k < 16; ++k) {
                    int c2 = 16 * p + k;
                    float2 wvv = W2P[c2 * WS + o];
                    double2 hv = *reinterpret_cast<const double2*>(&smd[D_H1 + 2 * c2]);
                    if (k & 1) { a2 += (double)wvv.x * hv.x; a3 += (double)wvv.y * hv.y; }
                    else       { a0 += (double)wvv.x * hv.x; a1 += (double)wvv.y * hv.y; }
                }
                double s = (a0 + a2) + (a1 + a3);
                s += __shfl_xor(s, 1, 64);
                s += __shfl_xor(s, 2, 64);
                s += b2r;
                double d;
                double h = lipswish_d(s, &d);
                if (p == 0) { smd[D_H2 + o] = h; smd[D_D2 + o] = d; }
            }
            __syncthreads();
            // ---- C: L3 forward, F kept in register ----
            double F_reg;
            {
                double a0 = 0.0, a1 = 0.0, a2 = 0.0, a3 = 0.0;
                #pragma unroll
                for (int q = 0; q < 32; ++q) {
                    float4 wvv = w3q[q];
                    double2 h0 = *reinterpret_cast<const double2*>(&smd[D_H2 + 4 * q]);
                    double2 h1 = *reinterpret_cast<const double2*>(&smd[D_H2 + 4 * q + 2]);
                    a0 += (double)wvv.x * h0.x;
                    a1 += (double)wvv.y * h0.y;
                    a2 += (double)wvv.z * h1.x;
                    a3 += (double)wvv.w * h1.y;
                }
                F_reg = tanh(b3t + (a0 + a2) + (a1 + a3));
                smd[D_FB + t] = F_reg;
            }
            __syncthreads();
            // ---- D: per-wave tangent chain (barrier-free) ----
            {
                // wm[wv_][ln]
                double wmv = 0.0;
                #pragma unroll
                for (int bb = 0; bb < 8; ++bb)
                    wmv += smd[D_CMAT + wv_ * 8 + bb] * smd[D_FB + bb * 64 + ln];
                smd[D_SWM + wv_ * 68 + ln] = wmv;
                __builtin_amdgcn_wave_barrier();
                // u1 rows ln, ln+64
                double s00 = 0.0, s01 = 0.0, s10 = 0.0, s11 = 0.0;
                #pragma unroll
                for (int e2 = 0; e2 < 32; ++e2) {
                    float2 wa = W1P[e2 * WS + ln];
                    float2 wb = W1P[e2 * WS + ln + 64];
                    double2 m = *reinterpret_cast<const double2*>(&smd[D_SWM + wv_ * 68 + 2 * e2]);
                    s00 += (double)wa.x * m.x;
                    s01 += (double)wa.y * m.y;
                    s10 += (double)wb.x * m.x;
                    s11 += (double)wb.y * m.y;
                }
                smd[D_SU1 + wv_ * 132 + ln]      = (s00 + s01) * smd[D_D1 + ln];
                smd[D_SU1 + wv_ * 132 + ln + 64] = (s10 + s11) * smd[D_D1 + ln + 64];
                __builtin_amdgcn_wave_barrier();
                // u2 rows ln, ln+64
                s00 = 0.0; s01 = 0.0; s10 = 0.0; s11 = 0.0;
                #pragma unroll
                for (int c2 = 0; c2 < 64; ++c2) {
                    float2 wa = W2P[c2 * WS + ln];
                    float2 wb = W2P[c2 * WS + ln + 64];
                    double2 u = *reinterpret_cast<const double2*>(&smd[D_SU1 + wv_ * 132 + 2 * c2]);
                    s00 += (double)wa.x * u.x;
                    s01 += (double)wa.y * u.y;
                    s10 += (double)wb.x * u.x;
                    s11 += (double)wb.y * u.y;
                }
                smd[D_SU2 + wv_ * 132 + ln]      = (s00 + s01) * smd[D_D2 + ln];
                smd[D_SU2 + wv_ * 132 + ln + 64] = (s10 + s11) * smd[D_D2 + ln + 64];
                __builtin_amdgcn_wave_barrier();
                // t3 for row t; fold v[a]*F into the write
                double a0 = 0.0, a1 = 0.0, a2 = 0.0, a3 = 0.0;
                #pragma unroll
                for (int q = 0; q < 32; ++q) {
                    float4 wvv = w3q[q];
                    double2 u0 = *reinterpret_cast<const double2*>(&smd[D_SU2 + wv_ * 132 + 4 * q]);
                    double2 u1 = *reinterpret_cast<const double2*>(&smd[D_SU2 + wv_ * 132 + 4 * q + 2]);
                    a0 += (double)wvv.x * u0.x;
                    a1 += (double)wvv.y * u0.y;
                    a2 += (double)wvv.z * u1.x;
                    a3 += (double)wvv.w * u1.y;
                }
                double t3 = (1.0 - F_reg * F_reg) * ((a0 + a2) + (a1 + a3));
                smd[D_T3 + t] = smd[D_VSIG + w * 36 + wv_] * F_reg + t3;
            }
            __syncthreads();
            // ---- E: combine + RK4 glue (+ next-window CMAT at stage 3) ----
            if (t < 64) {
                double g = 0.0;
                #pragma unroll
                for (int a = 0; a < 8; ++a) g += smd[D_T3 + a * 64 + t];
                double y = smd[D_YCUR + t];
                if (stage == 0)      { smd[D_KACC + t] = g;        smd[D_YBUF + t] = y + 0.5 * g; }
                else if (stage == 1) { smd[D_KACC + t] += 2.0 * g; smd[D_YBUF + t] = y + 0.5 * g; }
                else if (stage == 2) { smd[D_KACC + t] += 2.0 * g; smd[D_YBUF + t] = y + g; }
                else {
                    double yn = y + (smd[D_KACC + t] + g) * (1.0 / 6.0);
                    smd[D_YCUR + t] = yn;
                    smd[D_YBUF + t] = yn;
                    smd[D_HID + (w + 1) * 64 + t] = yn;
                }
            } else if (t < 128 && stage == 3 && w < 15) {
                int idx = t - 64;
                int a = idx >> 3, bb = idx & 7;
                double cv = 0.0;
                if (a != bb) {
                    int i = a < bb ? a : bb;
                    int j = a < bb ? bb : a;
                    int pidx = 7 * i - (i * (i - 1)) / 2 + (j - i - 1);
                    double vv = smd[D_VSIG + (w + 1) * 36 + 8 + pidx];
                    cv = (a > bb) ? vv : -vv;
                }
                smd[D_CMAT + idx] = cv;
            }
            __syncthreads();
        }
    }

    // ==== readout ====
    for (int idx = t; idx < 544; idx += NT) {
        int s = idx >> 5, oo = idx & 31;
        double acc = (double)ro_b[oo];
        const float* wr = ro_w + oo * 64;
        const double* hr = &smd[D_HID + s * 64];
        #pragma unroll
        for (int d = 0; d < 64; ++d) acc += (double)wr[d] * hr[d];
        out[(size_t)b * 544 + idx] = (float)acc;
    }
}

extern "C" void kernel_launch(void* const* d_in, const int* in_sizes, int n_in,
                              void* d_out, int out_size, void* d_ws, size_t ws_size,
                              hipStream_t stream) {
    const float* x     = (const float*)d_in[0];
    const float* ic_w1 = (const float*)d_in[1];
    const float* ic_b1 = (const float*)d_in[2];
    const float* ic_w2 = (const float*)d_in[3];
    const float* ic_b2 = (const float*)d_in[4];
    const float* ic_w3 = (const float*)d_in[5];
    const float* ic_b3 = (const float*)d_in[6];
    const float* vf_w1 = (const float*)d_in[7];
    const float* vf_b1 = (const float*)d_in[8];
    const float* vf_w2 = (const float*)d_in[9];
    const float* vf_b2 = (const float*)d_in[10];
    const float* vf_w3 = (const float*)d_in[11];
    const float* vf_b3 = (const float*)d_in[12];
    const float* ro_w  = (const float*)d_in[13];
    const float* ro_b  = (const float*)d_in[14];
    float* out = (float*)d_out;

    int B = in_sizes[0] / (257 * 8);
    size_t shmem = (size_t)SMEM_BYTES;
    hipFuncSetAttribute(reinterpret_cast<const void*>(ncde_solve),
                        hipFuncAttributeMaxDynamicSharedMemorySize, (int)shmem);
    hipLaunchKernelGGL(ncde_solve, dim3(B), dim3(NT), shmem, stream,
                       x, ic_w1, ic_b1, ic_w2, ic_b2, ic_w3, ic_b3,
                       vf_w1, vf_b1, vf_w2, vf_b2, vf_w3, vf_b3, ro_w, ro_b, out);
}